// Round 17
// baseline (27.732 us; speedup 1.0000x reference)
//
#include <hip/hip_runtime.h>

#define N 256
#define LANES 64
#define FRONT 128        // front-pad pairs per region
#define NPAIRS 260       // FRONT + 128 real + 4 tail pad

typedef float f32x2 __attribute__((ext_vector_type(2)));
typedef float f32x4 __attribute__((ext_vector_type(4)));

// DPP wave_shr:1 — lane i gets src[i-1]; lane 0 gets +INF.
__device__ __forceinline__ float dpp_shr1_inf(float v) {
    return __int_as_float(__builtin_amdgcn_update_dpp(
        0x7f800000, __float_as_int(v), 0x138 /*wave_shr:1*/, 0xf, 0xf, false));
}

// Bidirectional Frechet DP (R16 structure), TWO BATCHES PER BLOCK interleaved
// step-by-step: batch S=1's independent instruction stream fills batch S=0's
// dependency-chain bubbles (min/max chain ~40 cyc vs 72 cyc issue). All
// per-batch state in [2]-arrays with compile-time indices (registers).
__global__ __launch_bounds__(128) void frechet_bi2(
    const float* __restrict__ x,   // [B, 256, 3]
    const float* __restrict__ y,   // [B, 256, 3]
    float* __restrict__ out)       // [B]
{
    const int b0  = 2 * blockIdx.x;
    const int tid = threadIdx.x;
    const int wid = tid >> 6;      // 0 = forward, 1 = reverse
    const int t   = tid & 63;      // lane

    const float INF = __builtin_inff();

    __shared__ f32x4 ldsY[2][2][2 * NPAIRS];   // [wid][batch]
    __shared__ float Fd253[2][256], Fd254[2][256], Rd254[2][256], Rd255[2][256];

    // ---- staging (both batches) ----
    #pragma unroll
    for (int bt = 0; bt < 2; ++bt) {
        const int bb = b0 + bt;
        f32x4* reg = ldsY[wid][bt];
        const f32x4 pad0 = {0.0f, 0.0f, 0.0f, 0.0f};
        const f32x4 pad1 = {0.0f, 0.0f, INF, INF};
        reg[2 * t]        = pad0;  reg[2 * t + 1]        = pad1;
        reg[2 * (t + 64)] = pad0;  reg[2 * (t + 64) + 1] = pad1;
        if (t < 4) {
            const int pp = FRONT + 128 + t;
            reg[2 * pp] = pad0;  reg[2 * pp + 1] = pad1;
        }
        #pragma unroll
        for (int k = 0; k < 2; ++k) {
            const int pr = t + 64 * k;               // real pair 0..127
            const int cbase = wid ? (254 - 2 * pr) : (2 * pr);
            const float2 v01 = *(const float2*)&y[(bb * N + cbase) * 3 + 0];
            const float2 v23 = *(const float2*)&y[(bb * N + cbase) * 3 + 2];
            const float2 v45 = *(const float2*)&y[(bb * N + cbase) * 3 + 4];
            float a0x, a0y, a0z, a1x, a1y, a1z;      // wid-uniform branch
            if (wid == 0) { a0x=v01.x; a0y=v01.y; a0z=v23.x; a1x=v23.y; a1y=v45.x; a1z=v45.y; }
            else          { a1x=v01.x; a1y=v01.y; a1z=v23.x; a0x=v23.y; a0y=v45.x; a0z=v45.y; }
            const float ss0 = a0x*a0x + a0y*a0y + a0z*a0z;
            const float ss1 = a1x*a1x + a1y*a1y + a1z*a1z;
            const int p = FRONT + pr;
            const f32x4 w0 = {a0x, a1x, a0y, a1y};
            const f32x4 w1 = {a0z, a1z, ss0, ss1};
            reg[2 * p]     = w0;
            reg[2 * p + 1] = w1;
        }
    }

    // x rows -> packed constants (both batches): cost = |x|^2+|y|^2-2x.y
    f32x2 xp0[2][4], xp1[2][4], xp2[2][4], sxp[2][4];
    #pragma unroll
    for (int bt = 0; bt < 2; ++bt) {
        const int bb = b0 + bt;
        const int rbase = wid ? (252 - 4 * t) : (4 * t);
        const float4 q0 = *(const float4*)&x[(bb * N + rbase) * 3 + 0];
        const float4 q1 = *(const float4*)&x[(bb * N + rbase) * 3 + 4];
        const float4 q2 = *(const float4*)&x[(bb * N + rbase) * 3 + 8];
        const float f[12] = {q0.x,q0.y,q0.z,q0.w, q1.x,q1.y,q1.z,q1.w, q2.x,q2.y,q2.z,q2.w};
        #pragma unroll
        for (int r = 0; r < 4; ++r) {
            float a0, a1, a2;                        // constant indices both arms
            if (wid == 0) { a0 = f[3*r+0];  a1 = f[3*r+1];  a2 = f[3*r+2]; }
            else          { a0 = f[9-3*r];  a1 = f[10-3*r]; a2 = f[11-3*r]; }
            const float m0 = -2.0f * a0, m1 = -2.0f * a1, m2 = -2.0f * a2;
            const float s  = a0 * a0 + a1 * a1 + a2 * a2;
            xp0[bt][r] = (f32x2){m0, m0};
            xp1[bt][r] = (f32x2){m1, m1};
            xp2[bt][r] = (f32x2){m2, m2};
            sxp[bt][r] = (f32x2){s, s};
        }
    }
    __syncthreads();

    // DP state per batch (all compile-time indexed)
    float lv[2][4], gq[2][2], hq[2][2], diagv[2], V[2][4], W[2][4];
    #pragma unroll
    for (int bt = 0; bt < 2; ++bt) {
        lv[bt][0] = INF; lv[bt][1] = INF; lv[bt][2] = INF; lv[bt][3] = INF;
        gq[bt][0] = INF; gq[bt][1] = INF; hq[bt][0] = INF; hq[bt][1] = INF;
        diagv[bt] = (t == 0) ? 0.0f : INF;   // seeds D[0][0]
    }

    #define STEP(S, Q0v, Q1v, Y0, Y1)                                             \
    {                                                                             \
        const float u0 = dpp_shr1_inf(Q0v);                                       \
        const float u1 = dpp_shr1_inf(Q1v);                                       \
        const f32x2 y0p = (Y0).xy, y1p = (Y0).zw;                                 \
        const f32x2 y2p = (Y1).xy, sab = (Y1).zw;                                 \
        const f32x2 c0p = __builtin_elementwise_fma(xp0[S][0], y0p,               \
                          __builtin_elementwise_fma(xp1[S][0], y1p,               \
                          __builtin_elementwise_fma(xp2[S][0], y2p, sxp[S][0] + sab))); \
        const f32x2 c1p = __builtin_elementwise_fma(xp0[S][1], y0p,               \
                          __builtin_elementwise_fma(xp1[S][1], y1p,               \
                          __builtin_elementwise_fma(xp2[S][1], y2p, sxp[S][1] + sab))); \
        const f32x2 c2p = __builtin_elementwise_fma(xp0[S][2], y0p,               \
                          __builtin_elementwise_fma(xp1[S][2], y1p,               \
                          __builtin_elementwise_fma(xp2[S][2], y2p, sxp[S][2] + sab))); \
        const f32x2 c3p = __builtin_elementwise_fma(xp0[S][3], y0p,               \
                          __builtin_elementwise_fma(xp1[S][3], y1p,               \
                          __builtin_elementwise_fma(xp2[S][3], y2p, sxp[S][3] + sab))); \
        V[S][0] = fmaxf(c0p.x, fminf(fminf(u0, lv[S][0]), diagv[S]));             \
        V[S][1] = fmaxf(c1p.x, fminf(fminf(V[S][0], lv[S][1]), lv[S][0]));        \
        V[S][2] = fmaxf(c2p.x, fminf(fminf(V[S][1], lv[S][2]), lv[S][1]));        \
        V[S][3] = fmaxf(c3p.x, fminf(fminf(V[S][2], lv[S][3]), lv[S][2]));        \
        W[S][0] = fmaxf(c0p.y, fminf(fminf(u1, V[S][0]), u0));                    \
        W[S][1] = fmaxf(c1p.y, fminf(fminf(W[S][0], V[S][1]), V[S][0]));          \
        W[S][2] = fmaxf(c2p.y, fminf(fminf(W[S][1], V[S][2]), V[S][1]));          \
        W[S][3] = fmaxf(c3p.y, fminf(fminf(W[S][2], V[S][3]), V[S][2]));          \
        lv[S][0] = W[S][0]; lv[S][1] = W[S][1];                                   \
        lv[S][2] = W[S][2]; lv[S][3] = W[S][3];                                   \
        Q0v = V[S][3]; Q1v = W[S][3];                                             \
        diagv[S] = u1;                                                            \
    }

    // prologue: 3 buffers per batch <- pairs q0, q0+1, q0+2
    const int q0i = FRONT - 2 * t;           // in [2, 128]
    const f32x4* bp0 = &ldsY[wid][0][2 * q0i];
    const f32x4* bp1 = &ldsY[wid][1][2 * q0i];
    f32x4 A00=bp0[0], A01=bp0[1], A10=bp0[2], A11=bp0[3], A20=bp0[4], A21=bp0[5];
    f32x4 B00=bp1[0], B01=bp1[1], B10=bp1[2], B11=bp1[3], B20=bp1[4], B21=bp1[5];
    bp0 += 6; bp1 += 6;

    // steps 0..119: 20 iterations x 6 steps, both batches interleaved
    #pragma unroll 1
    for (int k = 0; k < 20; ++k) {
        STEP(0, gq[0][0], gq[0][1], A00, A01); STEP(1, gq[1][0], gq[1][1], B00, B01);
        A00=bp0[0];  A01=bp0[1];  B00=bp1[0];  B01=bp1[1];
        STEP(0, hq[0][0], hq[0][1], A10, A11); STEP(1, hq[1][0], hq[1][1], B10, B11);
        A10=bp0[2];  A11=bp0[3];  B10=bp1[2];  B11=bp1[3];
        STEP(0, gq[0][0], gq[0][1], A20, A21); STEP(1, gq[1][0], gq[1][1], B20, B21);
        A20=bp0[4];  A21=bp0[5];  B20=bp1[4];  B21=bp1[5];
        STEP(0, hq[0][0], hq[0][1], A00, A01); STEP(1, hq[1][0], hq[1][1], B00, B01);
        A00=bp0[6];  A01=bp0[7];  B00=bp1[6];  B01=bp1[7];
        STEP(0, gq[0][0], gq[0][1], A10, A11); STEP(1, gq[1][0], gq[1][1], B10, B11);
        A10=bp0[8];  A11=bp0[9];  B10=bp1[8];  B11=bp1[9];
        STEP(0, hq[0][0], hq[0][1], A20, A21); STEP(1, hq[1][0], hq[1][1], B20, B21);
        A20=bp0[10]; A21=bp0[11]; B20=bp1[10]; B21=bp1[11];
        bp0 += 12; bp1 += 12;
    }
    // steps 120..124 with reloads
    STEP(0, gq[0][0], gq[0][1], A00, A01); STEP(1, gq[1][0], gq[1][1], B00, B01);
    A00=bp0[0]; A01=bp0[1]; B00=bp1[0]; B01=bp1[1];                       // s=120
    STEP(0, hq[0][0], hq[0][1], A10, A11); STEP(1, hq[1][0], hq[1][1], B10, B11);
    A10=bp0[2]; A11=bp0[3]; B10=bp1[2]; B11=bp1[3];                       // s=121
    STEP(0, gq[0][0], gq[0][1], A20, A21); STEP(1, gq[1][0], gq[1][1], B20, B21);
    A20=bp0[4]; A21=bp0[5]; B20=bp1[4]; B21=bp1[5];                       // s=122
    STEP(0, hq[0][0], hq[0][1], A00, A01); STEP(1, hq[1][0], hq[1][1], B00, B01);
    A00=bp0[6]; A01=bp0[7]; B00=bp1[6]; B01=bp1[7];                       // s=123
    STEP(0, gq[0][0], gq[0][1], A10, A11); STEP(1, gq[1][0], gq[1][1], B10, B11);
    A10=bp0[8]; A11=bp0[9]; B10=bp1[8]; B11=bp1[9];                       // s=124

    // peeled capture steps (schedule verbatim from verified R16)
    STEP(0, hq[0][0], hq[0][1], A20, A21); STEP(1, hq[1][0], hq[1][1], B20, B21); // s=125
    if (wid == 0) {
        Fd253[0][4*t+2]=W[0][2]; Fd253[0][4*t+3]=V[0][3]; Fd254[0][4*t+3]=W[0][3];
        Fd253[1][4*t+2]=W[1][2]; Fd253[1][4*t+3]=V[1][3]; Fd254[1][4*t+3]=W[1][3];
    } else {
        Rd254[0][4*t+3]=W[0][3];
        Rd254[1][4*t+3]=W[1][3];
    }
    STEP(0, gq[0][0], gq[0][1], A00, A01); STEP(1, gq[1][0], gq[1][1], B00, B01); // s=126
    if (wid == 0) {
        Fd253[0][4*t]=W[0][0]; Fd253[0][4*t+1]=V[0][1]; Fd254[0][4*t+1]=W[0][1]; Fd254[0][4*t+2]=V[0][2];
        Fd253[1][4*t]=W[1][0]; Fd253[1][4*t+1]=V[1][1]; Fd254[1][4*t+1]=W[1][1]; Fd254[1][4*t+2]=V[1][2];
    } else {
        Rd255[0][4*t+2]=W[0][2]; Rd255[0][4*t+3]=V[0][3]; Rd254[0][4*t+1]=W[0][1]; Rd254[0][4*t+2]=V[0][2];
        Rd255[1][4*t+2]=W[1][2]; Rd255[1][4*t+3]=V[1][3]; Rd254[1][4*t+1]=W[1][1]; Rd254[1][4*t+2]=V[1][2];
    }
    STEP(0, hq[0][0], hq[0][1], A10, A11); STEP(1, hq[1][0], hq[1][1], B10, B11); // s=127
    if (wid == 0) {
        Fd254[0][4*t]=V[0][0];
        Fd254[1][4*t]=V[1][0];
    } else {
        Rd255[0][4*t]=W[0][0]; Rd255[0][4*t+1]=V[0][1]; Rd254[0][4*t]=V[0][0];
        Rd255[1][4*t]=W[1][0]; Rd255[1][4*t+1]=V[1][1]; Rd254[1][4*t]=V[1][0];
    }

    #undef STEP

    __syncthreads();

    // combine: wave wid combines batch wid (formula verbatim from R16)
    {
        const int bt = wid;
        float m = INF;
        #pragma unroll
        for (int kk = 0; kk < 4; ++kk) {
            const int r  = 4 * t + kk;
            const int i2 = (254 - r) < 0 ? 0 : (254 - r);
            const float rn = Rd255[bt][i2];
            const float ta = fmaxf(Fd254[bt][r],
                                   fminf(fminf(Rd255[bt][255 - r], rn), Rd254[bt][i2]));
            const float tb = fmaxf(Fd253[bt][r], rn);
            m = fminf(m, fminf(ta, tb));
        }
        #pragma unroll
        for (int off = 32; off >= 1; off >>= 1)
            m = fminf(m, __shfl_xor(m, off));
        if (t == 0) out[b0 + bt] = m;
    }
}

extern "C" void kernel_launch(void* const* d_in, const int* in_sizes, int n_in,
                              void* d_out, int out_size, void* d_ws, size_t ws_size,
                              hipStream_t stream) {
    const float* x = (const float*)d_in[0];
    const float* y = (const float*)d_in[1];
    float* out = (float*)d_out;

    const int B = in_sizes[0] / (N * 3);   // 128
    frechet_bi2<<<B / 2, 128, 0, stream>>>(x, y, out);
}

// Round 18
// 17.524 us; speedup vs baseline: 1.5825x; 1.5825x over previous
//
#include <hip/hip_runtime.h>

#define N 256
#define LANES 64
#define FRONT 128        // front-pad pairs per region
#define NPAIRS 260       // FRONT + 128 real + 4 tail pad
#define NSTEP 128        // uniform step count (skew-2 absorbs the ramp)

typedef float f32x2 __attribute__((ext_vector_type(2)));
typedef float f32x4 __attribute__((ext_vector_type(4)));

// DPP wave_shr:1 — lane i gets src[i-1]; lane 0 gets +INF.
__device__ __forceinline__ float dpp_shr1_inf(float v) {
    return __int_as_float(__builtin_amdgcn_update_dpp(
        0x7f800000, __float_as_int(v), 0x138 /*wave_shr:1*/, 0xf, 0xf, false));
}

// Bidirectional Frechet DP. Wave 0: forward DP on triangle i+j<=254 (+253
// captures). Wave 1: reverse DP (same recurrence on reversed x,y) on the
// complementary triangle. Skew-2: lane t processes pair p at step 2t+p, so
// every lane finishes its triangle at step 127 -> 128 uniform steps (vs 191
// for the full sweep). Cross-lane "up" values are delayed 2 steps via g/h
// delay-register renaming (no movs). Cut combine (exact min/max algebra):
//  ans = min_r [ max(F254[r], min(R255[255-r], R255[254-r], R254[254-r])),
//                max(F253[r], R255[254-r]) ]
__global__ __launch_bounds__(128) void frechet_bidir(
    const float* __restrict__ x,   // [B, 256, 3]
    const float* __restrict__ y,   // [B, 256, 3]
    float* __restrict__ out)       // [B]
{
    const int b   = blockIdx.x;
    const int tid = threadIdx.x;
    const int wid = tid >> 6;      // 0 = forward, 1 = reverse
    const int t   = tid & 63;      // lane

    const float INF = __builtin_inff();

    // per-wave y regions (component-interleaved pairs) + cut-capture arrays
    __shared__ f32x4 ldsY[2][2 * NPAIRS];
    __shared__ float Fd253[256], Fd254[256], Rd254[256], Rd255[256];

    f32x4* reg = ldsY[wid];

    // pads: cost components 0, ss=+INF -> cell = +INF (DP boundary)
    {
        const f32x4 pad0 = {0.0f, 0.0f, 0.0f, 0.0f};
        const f32x4 pad1 = {0.0f, 0.0f, INF, INF};
        reg[2 * t]            = pad0;  reg[2 * t + 1]            = pad1;
        reg[2 * (t + 64)]     = pad0;  reg[2 * (t + 64) + 1]     = pad1;
        if (t < 4) {
            const int pp = FRONT + 128 + t;
            reg[2 * pp] = pad0;  reg[2 * pp + 1] = pad1;
        }
    }

    // stage oriented y: wave 0 cols c, wave 1 cols 255-c
    #pragma unroll
    for (int k = 0; k < 2; ++k) {
        const int pr = t + 64 * k;           // real pair 0..127
        const int c0 = 2 * pr, c1 = 2 * pr + 1;
        const int oc0 = wid ? (255 - c0) : c0;
        const int oc1 = wid ? (255 - c1) : c1;
        const float a0x = y[(b * N + oc0) * 3 + 0];
        const float a0y = y[(b * N + oc0) * 3 + 1];
        const float a0z = y[(b * N + oc0) * 3 + 2];
        const float a1x = y[(b * N + oc1) * 3 + 0];
        const float a1y = y[(b * N + oc1) * 3 + 1];
        const float a1z = y[(b * N + oc1) * 3 + 2];
        const float ss0 = a0x*a0x + a0y*a0y + a0z*a0z;
        const float ss1 = a1x*a1x + a1y*a1y + a1z*a1z;
        const int p = FRONT + pr;
        const f32x4 w0 = {a0x, a1x, a0y, a1y};
        const f32x4 w1 = {a0z, a1z, ss0, ss1};
        reg[2 * p]     = w0;
        reg[2 * p + 1] = w1;
    }

    // oriented x rows 4t..4t+3 -> packed constants: cost = |x|^2+|y|^2-2x.y
    f32x2 xp0[4], xp1[4], xp2[4], sxp[4];
    #pragma unroll
    for (int r = 0; r < 4; ++r) {
        const int orow = wid ? (255 - (4 * t + r)) : (4 * t + r);
        const float a0 = x[(b * N + orow) * 3 + 0];
        const float a1 = x[(b * N + orow) * 3 + 1];
        const float a2 = x[(b * N + orow) * 3 + 2];
        const float m0 = -2.0f * a0, m1 = -2.0f * a1, m2 = -2.0f * a2;
        const float s  = a0 * a0 + a1 * a1 + a2 * a2;
        xp0[r].x = m0; xp0[r].y = m0;
        xp1[r].x = m1; xp1[r].y = m1;
        xp2[r].x = m2; xp2[r].y = m2;
        sxp[r].x = s;  sxp[r].y = s;
    }
    __syncthreads();

    float lv0 = INF, lv1 = INF, lv2 = INF, lv3 = INF;
    float g0 = INF, g1 = INF;              // cb delayed 2 steps (even parity)
    float h0 = INF, h1 = INF;              // cb delayed 2 steps (odd parity)
    float diagv = (t == 0) ? 0.0f : INF;   // seeds D[0][0]
    float V0, V1, V2, V3, W0, W1, W2, W3;  // persistent step outputs

    // one DP step; Q0v/Q1v = delay regs (read 2-step-old cb, then hold new cb)
    #define STEP(Q0v, Q1v, Y0, Y1)                                            \
    {                                                                         \
        const float u0 = dpp_shr1_inf(Q0v);                                   \
        const float u1 = dpp_shr1_inf(Q1v);                                   \
        const f32x2 y0p = (Y0).xy, y1p = (Y0).zw;                             \
        const f32x2 y2p = (Y1).xy, sab = (Y1).zw;                             \
        const f32x2 c0p = __builtin_elementwise_fma(xp0[0], y0p,              \
                          __builtin_elementwise_fma(xp1[0], y1p,              \
                          __builtin_elementwise_fma(xp2[0], y2p, sxp[0] + sab))); \
        const f32x2 c1p = __builtin_elementwise_fma(xp0[1], y0p,              \
                          __builtin_elementwise_fma(xp1[1], y1p,              \
                          __builtin_elementwise_fma(xp2[1], y2p, sxp[1] + sab))); \
        const f32x2 c2p = __builtin_elementwise_fma(xp0[2], y0p,              \
                          __builtin_elementwise_fma(xp1[2], y1p,              \
                          __builtin_elementwise_fma(xp2[2], y2p, sxp[2] + sab))); \
        const f32x2 c3p = __builtin_elementwise_fma(xp0[3], y0p,              \
                          __builtin_elementwise_fma(xp1[3], y1p,              \
                          __builtin_elementwise_fma(xp2[3], y2p, sxp[3] + sab))); \
        V0 = fmaxf(c0p.x, fminf(fminf(u0, lv0), diagv));                      \
        V1 = fmaxf(c1p.x, fminf(fminf(V0, lv1), lv0));                        \
        V2 = fmaxf(c2p.x, fminf(fminf(V1, lv2), lv1));                        \
        V3 = fmaxf(c3p.x, fminf(fminf(V2, lv3), lv2));                        \
        W0 = fmaxf(c0p.y, fminf(fminf(u1, V0), u0));                          \
        W1 = fmaxf(c1p.y, fminf(fminf(W0, V1), V0));                          \
        W2 = fmaxf(c2p.y, fminf(fminf(W1, V2), V1));                          \
        W3 = fmaxf(c3p.y, fminf(fminf(W2, V3), V2));                          \
        lv0 = W0; lv1 = W1; lv2 = W2; lv3 = W3;                               \
        Q0v = V3; Q1v = W3;                                                   \
        diagv = u1;                                                           \
    }

    // prologue: A,B,C <- LDS pairs q0, q0+1, q0+2 (steps 0,1,2)
    const int q0 = FRONT - 2 * t;          // in [2, 128]
    const f32x4* bp = &reg[2 * q0];
    f32x4 yA0 = bp[0], yA1 = bp[1];
    f32x4 yB0 = bp[2], yB1 = bp[3];
    f32x4 yC0 = bp[4], yC1 = bp[5];
    bp += 6;

    // steps 0..119: 20 iterations x 6 steps (g/h parity period = 2, buffers 3)
    #pragma unroll 1
    for (int k = 0; k < 20; ++k) {
        STEP(g0, g1, yA0, yA1); yA0 = bp[0];  yA1 = bp[1];
        STEP(h0, h1, yB0, yB1); yB0 = bp[2];  yB1 = bp[3];
        STEP(g0, g1, yC0, yC1); yC0 = bp[4];  yC1 = bp[5];
        STEP(h0, h1, yA0, yA1); yA0 = bp[6];  yA1 = bp[7];
        STEP(g0, g1, yB0, yB1); yB0 = bp[8];  yB1 = bp[9];
        STEP(h0, h1, yC0, yC1); yC0 = bp[10]; yC1 = bp[11];
        bp += 12;
    }
    // steps 120..124 with reloads
    STEP(g0, g1, yA0, yA1); yA0 = bp[0]; yA1 = bp[1];   // s=120
    STEP(h0, h1, yB0, yB1); yB0 = bp[2]; yB1 = bp[3];   // s=121
    STEP(g0, g1, yC0, yC1); yC0 = bp[4]; yC1 = bp[5];   // s=122
    STEP(h0, h1, yA0, yA1); yA0 = bp[6]; yA1 = bp[7];   // s=123
    STEP(g0, g1, yB0, yB1); yB0 = bp[8]; yB1 = bp[9];   // s=124
    // peeled capture steps (pair 125-2t, 126-2t, 127-2t; invalid -> INF)
    STEP(h0, h1, yC0, yC1);                              // s=125
    if (wid == 0) { Fd253[4*t+2] = W2; Fd253[4*t+3] = V3; Fd254[4*t+3] = W3; }
    else          { Rd254[4*t+3] = W3; }
    STEP(g0, g1, yA0, yA1);                              // s=126
    if (wid == 0) { Fd253[4*t]   = W0; Fd253[4*t+1] = V1;
                    Fd254[4*t+1] = W1; Fd254[4*t+2] = V2; }
    else          { Rd255[4*t+2] = W2; Rd255[4*t+3] = V3;
                    Rd254[4*t+1] = W1; Rd254[4*t+2] = V2; }
    STEP(h0, h1, yB0, yB1);                              // s=127
    if (wid == 0) { Fd254[4*t]   = V0; }
    else          { Rd255[4*t]   = W0; Rd255[4*t+1] = V1; Rd254[4*t] = V0; }

    #undef STEP

    __syncthreads();

    // combine (wave 0): min over cut edges; invalid entries are INF
    if (wid == 0) {
        float m = INF;
        #pragma unroll
        for (int k = 0; k < 4; ++k) {
            const int r  = 4 * t + k;
            const int i2 = (254 - r) < 0 ? 0 : (254 - r);   // clamp (r=255 terms are INF)
            const float rn = Rd255[i2];
            const float ta = fmaxf(Fd254[r],
                                   fminf(fminf(Rd255[255 - r], rn), Rd254[i2]));
            const float tb = fmaxf(Fd253[r], rn);
            m = fminf(m, fminf(ta, tb));
        }
        #pragma unroll
        for (int off = 32; off >= 1; off >>= 1)
            m = fminf(m, __shfl_xor(m, off));
        if (t == 0) out[b] = m;
    }
}

extern "C" void kernel_launch(void* const* d_in, const int* in_sizes, int n_in,
                              void* d_out, int out_size, void* d_ws, size_t ws_size,
                              hipStream_t stream) {
    const float* x = (const float*)d_in[0];
    const float* y = (const float*)d_in[1];
    float* out = (float*)d_out;

    const int B = in_sizes[0] / (N * 3);   // 128
    frechet_bidir<<<B, 128, 0, stream>>>(x, y, out);
}